// Round 16
// baseline (218.557 us; speedup 1.0000x reference)
//
#include <hip/hip_runtime.h>

#define NB 8
#define NS 1024
#define NH 32
#define NKV 8
#define ND 128
#define QT 256     // attn: 8 waves x 32 q-rows
#define KT 64

typedef _Float16 f16x8 __attribute__((ext_vector_type(8)));
typedef _Float16 f16x4 __attribute__((ext_vector_type(4)));
typedef __fp16 fp16x2 __attribute__((ext_vector_type(2)));
typedef float f32x16 __attribute__((ext_vector_type(16)));
typedef unsigned int u32x2 __attribute__((ext_vector_type(2)));

__device__ __forceinline__ float exp2fast(float x) { return __builtin_amdgcn_exp2f(x); }
__device__ __forceinline__ unsigned pkrtz_u(float a, float b) {
  union { fp16x2 h; unsigned u; } c;
  c.h = __builtin_amdgcn_cvt_pkrtz(a, b);
  return c.u;
}
__device__ __forceinline__ u32x2 swap32(float x) {
  union { float f; unsigned u; } c; c.f = x;
  return __builtin_amdgcn_permlane32_swap(c.u, c.u, false, false);
}
__device__ __forceinline__ float asf(unsigned u) { union { unsigned u; float f; } c; c.u = u; return c.f; }
__device__ __forceinline__ int gsw3(int d) { return ((d ^ (d >> 3)) & 7) << 4; }

// async global->LDS, 16B per lane; LDS dest = wave-uniform base + lane*16
__device__ __forceinline__ void gload16(const void* g, void* l) {
  __builtin_amdgcn_global_load_lds(
      (const __attribute__((address_space(1))) unsigned int*)g,
      (__attribute__((address_space(3))) unsigned int*)l, 16, 0, 0);
}

// ---- pre-pass A: K f32 [t][dkv] -> f16 [b][hkv][kv][256B row, PRE-SWIZZLED (2d)^((kv&15)<<4)] ----
__global__ __launch_bounds__(256)
void cvt_k(const float* __restrict__ kg, char* __restrict__ wsK)
{
  int g = blockIdx.x * 256 + threadIdx.x;       // float4 index
  int t = g >> 8, c4 = g & 255;
  int b = t >> 10, kv = t & 1023;
  int hkv = c4 >> 5, d4 = (c4 & 31) * 4;
  float4 v = ((const float4*)kg)[g];
  union { f16x4 h; unsigned long long u; } p;
  p.h[0] = (_Float16)v.x; p.h[1] = (_Float16)v.y;
  p.h[2] = (_Float16)v.z; p.h[3] = (_Float16)v.w;
  size_t row = (size_t)(b * NKV + hkv) * NS + kv;
  *(unsigned long long*)(wsK + row * 256 + ((d4 * 2) ^ ((kv & 15) << 4))) = p.u;
}

// ---- pre-pass B: V f32 -> f16 V^T, tile-blocked [b][hkv][kvt][d][kv64], rows PRE-SWIZZLED gsw3 ----
__global__ __launch_bounds__(256)
void cvt_vt(const float* __restrict__ vg, _Float16* __restrict__ wsV)
{
  __shared__ _Float16 T[ND][KT];                // 16 KB transpose tile
  const int tid = threadIdx.x;
  const int kvt = blockIdx.x, b = blockIdx.y, hkv = blockIdx.z;
#pragma unroll
  for (int pass = 0; pass < 8; ++pass) {
    int kvr = (tid >> 5) + pass * 8;            // 0..63
    int d4  = (tid & 31) * 4;
    float4 v = ((const float4*)vg)[(size_t)(b * NS + kvt * KT + kvr) * 256 + hkv * 32 + (tid & 31)];
    T[d4 + 0][kvr] = (_Float16)v.x;
    T[d4 + 1][kvr] = (_Float16)v.y;
    T[d4 + 2][kvr] = (_Float16)v.z;
    T[d4 + 3][kvr] = (_Float16)v.w;
  }
  __syncthreads();
  _Float16* out = wsV + ((size_t)(b * NKV + hkv) * 16 + kvt) * 8192;   // 16KB tile block
#pragma unroll
  for (int pass = 0; pass < 4; ++pass) {
    int u = tid + pass * 256;                   // 16B chunk id
    int d = u >> 3, c = u & 7;
    int kv8 = ((c * 16) ^ gsw3(d)) >> 1;        // source kv octet for this swizzled slot
    *(f16x8*)(out + d * 64 + c * 8) = *(const f16x8*)&T[d][kv8];
  }
}

// ---- attention: dbuf LDS via global_load_lds; counted vmcnt + RAW barriers (T4) ----
__global__ __launch_bounds__(512, 1)
void attn_fwd(const float* __restrict__ qg, const char* __restrict__ wsK,
              const char* __restrict__ wsV, float* __restrict__ og)
{
  __shared__ __align__(16) _Float16 Klds[2][KT * 128];   // 2x16KB
  __shared__ __align__(16) _Float16 Vlds[2][128 * 64];   // 2x16KB

  const int tid  = threadIdx.x;
  const int lane = tid & 63;
  const int w    = tid >> 6;
  const int lq   = lane & 31;
  const int hi   = lane >> 5;

  const int qtile = blockIdx.x;   // 0..3
  const int b     = blockIdx.y;
  const int h     = blockIdx.z;
  const int hkv   = h >> 2;
  const int bh    = b * NKV + hkv;

  const int qr0w = qtile * QT + w * 32;
  const int qrow = qr0w + lq;

  const float QS = 0.08838834764831845f * 1.4426950408889634f;  // scale * log2(e)

  // ---- Q fragments (B-frag: col=q=lane&31, k = 8*hi + i per 16-d block) ----
  f16x8 qf[8];
  {
    const float* qp = qg + (size_t)(b * NS + qrow) * (NH * ND) + h * ND + hi * 8;
#pragma unroll
    for (int dblk = 0; dblk < 8; ++dblk) {
      float4 f0 = *(const float4*)(qp + dblk * 16);
      float4 f1 = *(const float4*)(qp + dblk * 16 + 4);
      f16x8 a;
      a[0] = (_Float16)(f0.x * QS); a[1] = (_Float16)(f0.y * QS);
      a[2] = (_Float16)(f0.z * QS); a[3] = (_Float16)(f0.w * QS);
      a[4] = (_Float16)(f1.x * QS); a[5] = (_Float16)(f1.y * QS);
      a[6] = (_Float16)(f1.z * QS); a[7] = (_Float16)(f1.w * QS);
      qf[dblk] = a;
    }
  }

  f32x16 acc[4];
#pragma unroll
  for (int nb = 0; nb < 4; ++nb)
#pragma unroll
    for (int r = 0; r < 16; ++r) acc[nb][r] = 0.f;
  float m_run = -1e30f, l_run = 0.f;

  const char* wsKb = wsK + (size_t)bh * NS * 256;        // K rows base for this (b,hkv)
  const char* wsVb = wsV + (size_t)bh * 16 * 16384;      // V tile blocks base

#define STAGE(TI, BUF)                                                     \
  {                                                                        \
    const char* gk = wsKb + (size_t)(TI) * 16384;                          \
    const char* gv = wsVb + (size_t)(TI) * 16384;                          \
    char* lk = (char*)&Klds[BUF][0] + w * 1024;                            \
    char* lv = (char*)&Vlds[BUF][0] + w * 1024;                            \
    gload16(gk + w * 1024 + lane * 16, lk);                                \
    gload16(gk + 8192 + w * 1024 + lane * 16, lk + 8192);                  \
    gload16(gv + w * 1024 + lane * 16, lv);                                \
    gload16(gv + 8192 + w * 1024 + lane * 16, lv + 8192);                  \
  }

  const int nt = (qtile + 1) * (QT / KT);

  // ---- prologue: stage tile 0, full drain once ----
  STAGE(0, 0);
  asm volatile("s_waitcnt vmcnt(0)" ::: "memory");
  __builtin_amdgcn_s_barrier();
  __builtin_amdgcn_sched_barrier(0);

  for (int ti = 0; ti < nt; ++ti) {
    const int kv0 = ti * KT;
    const int cur = ti & 1;
    const bool hn = (ti + 1 < nt);

    // T4: issue next tile's DMA, then wait ONLY the 4 oldest (tile ti's) —
    // the 4 new loads stay in flight across both barriers and all of compute.
    if (hn) {
      STAGE(ti + 1, cur ^ 1);
      asm volatile("s_waitcnt vmcnt(4)" ::: "memory");
    } else {
      asm volatile("s_waitcnt vmcnt(0)" ::: "memory");
    }
    __builtin_amdgcn_s_barrier();          // raw: no implicit drain
    __builtin_amdgcn_sched_barrier(0);

    if (kv0 <= qr0w + 31) {                // wave-uniform causal tile skip
      const char* Kb = (const char*)&Klds[cur][0];
      const char* Vb = (const char*)&Vlds[cur][0];

      // ---- swapped QK^T: P^T[kv][q] ----
      f32x16 s[2];
#pragma unroll
      for (int r = 0; r < 16; ++r) { s[0][r] = 0.f; s[1][r] = 0.f; }
      __builtin_amdgcn_s_setprio(1);
#pragma unroll
      for (int dblk = 0; dblk < 8; ++dblk) {
        int soff = (dblk * 32 + 16 * hi) ^ ((lq & 15) << 4);
        f16x8 k0 = *(const f16x8*)(Kb + lq * 256 + soff);
        f16x8 k1 = *(const f16x8*)(Kb + (lq + 32) * 256 + soff);
        s[0] = __builtin_amdgcn_mfma_f32_32x32x16_f16(k0, qf[dblk], s[0], 0, 0, 0);
        s[1] = __builtin_amdgcn_mfma_f32_32x32x16_f16(k1, qf[dblk], s[1], 0, 0, 0);
      }
      __builtin_amdgcn_s_setprio(0);

      // ---- causal mask (diagonal tiles only) ----
      if (kv0 + KT - 1 > qr0w) {
        const int thr = qrow - kv0;
#pragma unroll
        for (int kb = 0; kb < 2; ++kb)
#pragma unroll
          for (int r = 0; r < 16; ++r) {
            int kvl = kb * 32 + (r & 3) + 8 * (r >> 2) + 4 * hi;
            if (kvl > thr) s[kb][r] = -1e30f;
          }
      }

      // ---- online softmax with defer-max (T13, THR=8 in log2 units) ----
      float pmax = s[0][0];
#pragma unroll
      for (int r = 1; r < 16; ++r) pmax = fmaxf(pmax, s[0][r]);
#pragma unroll
      for (int r = 0; r < 16; ++r) pmax = fmaxf(pmax, s[1][r]);
      {
        u32x2 pr = swap32(pmax);
        pmax = fmaxf(asf(pr[0]), asf(pr[1]));
      }
      const int need = !__all(pmax <= m_run + 8.0f);
      if (need) {
        const float mn = fmaxf(m_run, pmax);
        const float al = exp2fast(m_run - mn);
        m_run = mn;
#pragma unroll
        for (int r = 0; r < 16; ++r) {
          int row = (r & 3) + 8 * (r >> 2) + 4 * hi;
          float a = __shfl(al, row, 64);
#pragma unroll
          for (int nb = 0; nb < 4; ++nb) acc[nb][r] *= a;
        }
        l_run *= al;
      }
      float rs = 0.f;
#pragma unroll
      for (int kb = 0; kb < 2; ++kb)
#pragma unroll
        for (int r = 0; r < 16; ++r) {
          float p = exp2fast(s[kb][r] - m_run);
          s[kb][r] = p;
          rs += p;
        }
      {
        u32x2 sr = swap32(rs);
        rs = asf(sr[0]) + asf(sr[1]);
      }
      l_run += rs;

      // ---- P -> A-fragments in-register (cvt_pk + permlane32_swap) ----
      f16x8 pa[4];
#pragma unroll
      for (int t = 0; t < 4; ++t) {
        const int kb = t >> 1, rb = (t & 1) * 8;
        unsigned w0 = pkrtz_u(s[kb][rb + 0], s[kb][rb + 1]);
        unsigned w1 = pkrtz_u(s[kb][rb + 2], s[kb][rb + 3]);
        unsigned w2 = pkrtz_u(s[kb][rb + 4], s[kb][rb + 5]);
        unsigned w3 = pkrtz_u(s[kb][rb + 6], s[kb][rb + 7]);
        u32x2 p02 = __builtin_amdgcn_permlane32_swap(w0, w2, false, false);
        u32x2 p13 = __builtin_amdgcn_permlane32_swap(w1, w3, false, false);
        union { unsigned u[4]; f16x8 v; } pw;
        pw.u[0] = p02[0]; pw.u[1] = p13[0]; pw.u[2] = p02[1]; pw.u[3] = p13[1];
        pa[t] = pw.v;
      }

      // ---- O += P V ----
      __builtin_amdgcn_s_setprio(1);
#pragma unroll
      for (int t = 0; t < 4; ++t) {
        int koff = t * 32 + 16 * hi;
#pragma unroll
        for (int nb = 0; nb < 4; ++nb) {
          int d = nb * 32 + lq;
          f16x8 vb = *(const f16x8*)(Vb + d * 128 + (koff ^ gsw3(d)));
          acc[nb] = __builtin_amdgcn_mfma_f32_32x32x16_f16(pa[t], vb, acc[nb], 0, 0, 0);
        }
      }
      __builtin_amdgcn_s_setprio(0);
    }

    __builtin_amdgcn_s_barrier();          // raw: protect buffers; prefetch stays in flight
    __builtin_amdgcn_sched_barrier(0);
  }

  // ---- epilogue: divide by l, coalesced f32 stores ----
  const float linv = 1.0f / l_run;
#pragma unroll
  for (int r = 0; r < 16; ++r) {
    int row = (r & 3) + 8 * (r >> 2) + 4 * hi;
    float li = __shfl(linv, row, 64);
    float* op = og + (size_t)(b * NS + qr0w + row) * (NH * ND) + h * ND + lq;
#pragma unroll
    for (int nb = 0; nb < 4; ++nb)
      op[nb * 32] = acc[nb][r] * li;
  }
#undef STAGE
}

extern "C" void kernel_launch(void* const* d_in, const int* in_sizes, int n_in,
                              void* d_out, int out_size, void* d_ws, size_t ws_size,
                              hipStream_t stream) {
  const float* q = (const float*)d_in[0];
  const float* k = (const float*)d_in[1];
  const float* v = (const float*)d_in[2];
  float* o = (float*)d_out;

  const size_t KSZ = (size_t)NB * NKV * NS * ND * sizeof(_Float16);  // 16.78 MB each
  if (ws_size < 2 * KSZ) return;     // fail loudly (output stays poisoned)
  char*     wsK = (char*)d_ws;
  _Float16* wsV = (_Float16*)((char*)d_ws + KSZ);

  cvt_k <<<dim3((NB * NS * 256) / 256), 256, 0, stream>>>(k, wsK);
  cvt_vt<<<dim3(NS / KT, NB, NKV),      256, 0, stream>>>(v, wsV);
  attn_fwd<<<dim3(NS / QT, NB, NH),     512, 0, stream>>>(q, wsK, (const char*)wsV, o);
}

// Round 18
// 202.833 us; speedup vs baseline: 1.0775x; 1.0775x over previous
//
#include <hip/hip_runtime.h>

#define NB 8
#define NS 1024
#define NH 32
#define NKV 8
#define ND 128
#define QT 128     // attn: 4 waves x 32 q-rows per block-phase, barrier-free
#define KT 64

typedef _Float16 f16x8 __attribute__((ext_vector_type(8)));
typedef __fp16 fp16x2 __attribute__((ext_vector_type(2)));
typedef float f32x16 __attribute__((ext_vector_type(16)));
typedef float f32x4v __attribute__((ext_vector_type(4)));   // plain vector: ok for nontemporal builtins
typedef unsigned int u32x2 __attribute__((ext_vector_type(2)));

__device__ __forceinline__ float exp2fast(float x) { return __builtin_amdgcn_exp2f(x); }
__device__ __forceinline__ unsigned pkrtz_u(float a, float b) {
  union { fp16x2 h; unsigned u; } c;
  c.h = __builtin_amdgcn_cvt_pkrtz(a, b);
  return c.u;
}
__device__ __forceinline__ u32x2 swap32(float x) {
  union { float f; unsigned u; } c; c.f = x;
  return __builtin_amdgcn_permlane32_swap(c.u, c.u, false, false);
}
__device__ __forceinline__ float asf(unsigned u) { union { unsigned u; float f; } c; c.u = u; return c.f; }

// ---- pre-pass A: K f32 [t][dkv] -> fragment-ordered f16 panels ----
// wsK layout: [panel=b*8+hkv][ti(16)][chunk=kb*8+dblk (16)][lane(64)][16B]
__global__ __launch_bounds__(256)
void cvt_kf(const float* __restrict__ kg, char* __restrict__ wsK)
{
  int g = blockIdx.x * 256 + threadIdx.x;      // one 16B f16 chunk each
  int t = g >> 7, c8 = g & 127;
  int hkv = c8 >> 4, d8 = c8 & 15;
  const float* src = kg + (size_t)t * 1024 + hkv * 128 + d8 * 8;
  float4 a = *(const float4*)src;
  float4 c = *(const float4*)(src + 4);
  f16x8 h8;
  h8[0] = (_Float16)a.x; h8[1] = (_Float16)a.y; h8[2] = (_Float16)a.z; h8[3] = (_Float16)a.w;
  h8[4] = (_Float16)c.x; h8[5] = (_Float16)c.y; h8[6] = (_Float16)c.z; h8[7] = (_Float16)c.w;
  int b  = t >> 10, kv = t & 1023;
  int ti = kv >> 6, kvl = kv & 63, kb = kvl >> 5, lq = kvl & 31;
  int dblk = d8 >> 1, hi = d8 & 1;
  size_t off = (((size_t)(b * 8 + hkv) * 16 + ti) * 16 + kb * 8 + dblk) * 1024 + (hi * 32 + lq) * 16;
  *(f16x8*)(wsK + off) = h8;
}

// ---- pre-pass B: V f32 -> fragment-ordered V^T f16 panels ----
// wsV layout: [panel][ti(16)][chunk=t*4+nb (16)][lane(64)][16B]
__global__ __launch_bounds__(256)
void cvt_vf(const float* __restrict__ vg, _Float16* __restrict__ wsV)
{
  __shared__ _Float16 T[ND][KT];               // 16 KB transpose tile
  const int tid = threadIdx.x;
  const int kvt = blockIdx.x, b = blockIdx.y, hkv = blockIdx.z;
#pragma unroll
  for (int pass = 0; pass < 8; ++pass) {
    int kvr = (tid >> 5) + pass * 8;
    int d4  = (tid & 31) * 4;
    float4 v = ((const float4*)vg)[(size_t)(b * NS + kvt * KT + kvr) * 256 + hkv * 32 + (tid & 31)];
    T[d4 + 0][kvr] = (_Float16)v.x;
    T[d4 + 1][kvr] = (_Float16)v.y;
    T[d4 + 2][kvr] = (_Float16)v.z;
    T[d4 + 3][kvr] = (_Float16)v.w;
  }
  __syncthreads();
  _Float16* out = wsV + ((size_t)(b * 8 + hkv) * 16 + kvt) * 8192;
#pragma unroll
  for (int pass = 0; pass < 4; ++pass) {
    int unit = tid + pass * 256;
    int c = unit >> 6, lane = unit & 63;
    int d = (c & 3) * 32 + (lane & 31);
    int kv8 = (c >> 2) * 16 + (lane >> 5) * 8;
    *(f16x8*)(out + unit * 8) = *(const f16x8*)&T[d][kv8];
  }
}

// ---- attention: barrier-free, LDS-free; K software-pipelined, nt Q/O streams ----
__global__ __launch_bounds__(256, 1)
void attn_fwd(const float* __restrict__ qg, const char* __restrict__ wsK,
              const char* __restrict__ wsV, float* __restrict__ og)
{
  // 1024 blocks; XCD swizzle: xcd=id&7 gets contiguous v-range -> 8 panels (4MB) per XCD L2
  const int id = blockIdx.x;
  const int v  = (id & 7) * 128 + (id >> 3);
  const int panel = v >> 4;                     // b*8+hkv
  const int sub   = v & 15;
  const int b     = panel >> 3;
  const int hkv   = panel & 7;
  const int h     = hkv * 4 + (sub & 3);
  const int qpair = sub >> 2;                   // 0..3

  const int tid  = threadIdx.x;
  const int lane = tid & 63;
  const int w    = tid >> 6;
  const int lq   = lane & 31;
  const int hi   = lane >> 5;

  const float QS = 0.08838834764831845f * 1.4426950408889634f;  // scale * log2(e)

  const char* wsKb = wsK + (size_t)panel * 16 * 16384;
  const char* wsVb = wsV + (size_t)panel * 16 * 16384;

#pragma unroll 1
  for (int ph = 0; ph < 2; ++ph) {
    const int qtile = ph ? (7 - qpair) : qpair;   // short phase then long phase
    const int qr0w = qtile * QT + w * 32;
    const int qrow = qr0w + lq;

    // ---- Q fragments (nontemporal: one-shot stream, keep L2 for K/V panels) ----
    f16x8 qf[8];
    {
      const float* qp = qg + (size_t)(b * NS + qrow) * (NH * ND) + h * ND + hi * 8;
#pragma unroll
      for (int dblk = 0; dblk < 8; ++dblk) {
        f32x4v f0 = __builtin_nontemporal_load((const f32x4v*)(qp + dblk * 16));
        f32x4v f1 = __builtin_nontemporal_load((const f32x4v*)(qp + dblk * 16 + 4));
        f16x8 a;
        a[0] = (_Float16)(f0[0] * QS); a[1] = (_Float16)(f0[1] * QS);
        a[2] = (_Float16)(f0[2] * QS); a[3] = (_Float16)(f0[3] * QS);
        a[4] = (_Float16)(f1[0] * QS); a[5] = (_Float16)(f1[1] * QS);
        a[6] = (_Float16)(f1[2] * QS); a[7] = (_Float16)(f1[3] * QS);
        qf[dblk] = a;
      }
    }

    f32x16 acc[4];
#pragma unroll
    for (int nb = 0; nb < 4; ++nb)
#pragma unroll
      for (int r = 0; r < 16; ++r) acc[nb][r] = 0.f;
    float m_run = -1e30f, l_run = 0.f;

    const int nt = qr0w / KT + 1;

    // ---- prologue: preload K fragments for tile 0 ----
    f16x8 kf[16];
#pragma unroll
    for (int c = 0; c < 16; ++c)
      kf[c] = *(const f16x8*)(wsKb + c * 1024 + lane * 16);

#pragma unroll 1
    for (int ti = 0; ti < nt; ++ti) {
      const char* vt_ = wsVb + (size_t)ti * 16384;

      // ---- swapped QK^T from preloaded kf ----
      f32x16 s[2];
#pragma unroll
      for (int r = 0; r < 16; ++r) { s[0][r] = 0.f; s[1][r] = 0.f; }
      __builtin_amdgcn_s_setprio(1);
#pragma unroll
      for (int dblk = 0; dblk < 8; ++dblk) {
        s[0] = __builtin_amdgcn_mfma_f32_32x32x16_f16(kf[dblk],     qf[dblk], s[0], 0, 0, 0);
        s[1] = __builtin_amdgcn_mfma_f32_32x32x16_f16(kf[8 + dblk], qf[dblk], s[1], 0, 0, 0);
      }
      __builtin_amdgcn_s_setprio(0);

      // ---- issue NEXT tile's K loads now: latency hides under softmax+PV ----
      if (ti + 1 < nt) {
        const char* ktn = wsKb + (size_t)(ti + 1) * 16384;
#pragma unroll
        for (int c = 0; c < 16; ++c)
          kf[c] = *(const f16x8*)(ktn + c * 1024 + lane * 16);
      }

      // ---- V fragments for this tile: latency hides under softmax ----
      f16x8 vf[16];
#pragma unroll
      for (int c = 0; c < 16; ++c)
        vf[c] = *(const f16x8*)(vt_ + c * 1024 + lane * 16);

      // ---- causal mask (final tile only) ----
      if (ti == nt - 1) {
        const int thr = qrow - ti * KT;
#pragma unroll
        for (int kb = 0; kb < 2; ++kb)
#pragma unroll
          for (int r = 0; r < 16; ++r) {
            int kvl = kb * 32 + (r & 3) + 8 * (r >> 2) + 4 * hi;
            if (kvl > thr) s[kb][r] = -1e30f;
          }
      }

      // ---- online softmax with defer-max (T13, THR=8 in log2 units) ----
      float pmax = s[0][0];
#pragma unroll
      for (int r = 1; r < 16; ++r) pmax = fmaxf(pmax, s[0][r]);
#pragma unroll
      for (int r = 0; r < 16; ++r) pmax = fmaxf(pmax, s[1][r]);
      {
        u32x2 pr = swap32(pmax);
        pmax = fmaxf(asf(pr[0]), asf(pr[1]));
      }
      const int need = !__all(pmax <= m_run + 8.0f);
      if (need) {
        const float mn = fmaxf(m_run, pmax);
        const float al = exp2fast(m_run - mn);
        m_run = mn;
#pragma unroll
        for (int r = 0; r < 16; ++r) {
          int row = (r & 3) + 8 * (r >> 2) + 4 * hi;
          float a = __shfl(al, row, 64);
#pragma unroll
          for (int nb = 0; nb < 4; ++nb) acc[nb][r] *= a;
        }
        l_run *= al;
      }
      float rs = 0.f;
#pragma unroll
      for (int kb = 0; kb < 2; ++kb)
#pragma unroll
        for (int r = 0; r < 16; ++r) {
          float p = exp2fast(s[kb][r] - m_run);
          s[kb][r] = p;
          rs += p;
        }
      {
        u32x2 sr = swap32(rs);
        rs = asf(sr[0]) + asf(sr[1]);
      }
      l_run += rs;

      // ---- P -> A-fragments in-register (cvt_pk + permlane32_swap) ----
      f16x8 pa[4];
#pragma unroll
      for (int t = 0; t < 4; ++t) {
        const int kb = t >> 1, rb = (t & 1) * 8;
        unsigned w0 = pkrtz_u(s[kb][rb + 0], s[kb][rb + 1]);
        unsigned w1 = pkrtz_u(s[kb][rb + 2], s[kb][rb + 3]);
        unsigned w2 = pkrtz_u(s[kb][rb + 4], s[kb][rb + 5]);
        unsigned w3 = pkrtz_u(s[kb][rb + 6], s[kb][rb + 7]);
        u32x2 p02 = __builtin_amdgcn_permlane32_swap(w0, w2, false, false);
        u32x2 p13 = __builtin_amdgcn_permlane32_swap(w1, w3, false, false);
        union { unsigned u[4]; f16x8 v; } pw;
        pw.u[0] = p02[0]; pw.u[1] = p13[0]; pw.u[2] = p02[1]; pw.u[3] = p13[1];
        pa[t] = pw.v;
      }

      // ---- O += P V ----
      __builtin_amdgcn_s_setprio(1);
#pragma unroll
      for (int t = 0; t < 4; ++t)
#pragma unroll
        for (int nb = 0; nb < 4; ++nb)
          acc[nb] = __builtin_amdgcn_mfma_f32_32x32x16_f16(pa[t], vf[t * 4 + nb], acc[nb], 0, 0, 0);
      __builtin_amdgcn_s_setprio(0);
    }

    // ---- epilogue: divide by l, nontemporal f32 stores ----
    const float linv = 1.0f / l_run;
#pragma unroll
    for (int r = 0; r < 16; ++r) {
      int row = (r & 3) + 8 * (r >> 2) + 4 * hi;
      float li = __shfl(linv, row, 64);
      float* op = og + (size_t)(b * NS + qr0w + row) * (NH * ND) + h * ND + lq;
#pragma unroll
      for (int nb = 0; nb < 4; ++nb)
        __builtin_nontemporal_store(acc[nb][r] * li, op + nb * 32);
    }
  }
}

extern "C" void kernel_launch(void* const* d_in, const int* in_sizes, int n_in,
                              void* d_out, int out_size, void* d_ws, size_t ws_size,
                              hipStream_t stream) {
  const float* q = (const float*)d_in[0];
  const float* k = (const float*)d_in[1];
  const float* v = (const float*)d_in[2];
  float* o = (float*)d_out;

  const size_t KSZ = (size_t)NB * NKV * NS * ND * sizeof(_Float16);  // 16.78 MB each
  if (ws_size < 2 * KSZ) return;     // fail loudly (output stays poisoned)
  char*     wsK = (char*)d_ws;
  _Float16* wsV = (_Float16*)((char*)d_ws + KSZ);

  cvt_kf<<<dim3((NB * NS * 128) / 256), 256, 0, stream>>>(k, wsK);
  cvt_vf<<<dim3(NS / KT, NB, NKV),      256, 0, stream>>>(v, wsV);
  attn_fwd<<<dim3(1024),                256, 0, stream>>>(q, wsK, (const char*)wsV, o);
}